// Round 3
// baseline (9409.207 us; speedup 1.0000x reference)
//
#include <hip/hip_runtime.h>

#define H_ 96
#define W_ 96
#define NV (H_ * W_)      // 9216 vertices per image
#define SORT_N 16384      // next pow2 >= NV
#define NT 256            // threads per block

// LDS layout: 65536 + 32768 + 18432 + 18432 = 135168 B (fits 160 KiB/WG on gfx950)
struct SMem {
  unsigned int   K[SORT_N];   // sortable keys; after sort: float bits of value at rank t
  unsigned short P[SORT_N];   // payload: vertex idx at rank t
  unsigned short rk[NV];      // vertex -> rank
  unsigned short par[NV];     // union-find parent over ranks (root == min rank == eldest)
};

__global__ __launch_bounds__(NT, 1)
void topo_entropy_kernel(const float* __restrict__ x, float* __restrict__ out) {
  __shared__ SMem sm;
  const int tid = threadIdx.x;
  const float* img = x + (size_t)blockIdx.x * NV;

  // ---- Phase 1: load values, build monotone sortable keys, init ----
  for (int i = tid; i < SORT_N; i += NT) {
    if (i < NV) {
      unsigned int b = __float_as_uint(img[i]);
      // IEEE-754 -> order-preserving unsigned key
      sm.K[i] = b ^ ((b & 0x80000000u) ? 0xFFFFFFFFu : 0x80000000u);
      sm.P[i] = (unsigned short)i;
      sm.par[i] = (unsigned short)i;
    } else {
      sm.K[i] = 0xFFFFFFFFu;   // +inf padding (input has no NaN)
      sm.P[i] = 0xFFFFu;
    }
  }
  __syncthreads();

  // ---- Phase 2: bitonic sort ascending on (K, P) ----
  for (int k = 2; k <= SORT_N; k <<= 1) {
    for (int j = k >> 1; j > 0; j >>= 1) {
      #pragma unroll 1
      for (int p = tid; p < (SORT_N / 2); p += NT) {
        int i = ((p & ~(j - 1)) << 1) | (p & (j - 1));
        int l = i | j;
        unsigned int ki = sm.K[i], kl = sm.K[l];
        bool up = ((i & k) == 0);
        bool sw = up ? (ki > kl) : (ki < kl);
        if (sw) {
          sm.K[i] = kl; sm.K[l] = ki;
          unsigned short tp = sm.P[i]; sm.P[i] = sm.P[l]; sm.P[l] = tp;
        }
      }
      __syncthreads();
    }
  }

  // ---- Phase 3: invert keys back to float bits (rank -> value), build rank LUT ----
  for (int t = tid; t < NV; t += NT) {
    unsigned int key = sm.K[t];
    sm.K[t] = key ^ ((key & 0x80000000u) ? 0x80000000u : 0xFFFFFFFFu);
    sm.rk[sm.P[t]] = (unsigned short)t;
  }
  __syncthreads();

  // ---- Phase 4: serial union-find over ranks (elder rule = min rank wins) ----
  if (tid == 0) {
    double T = 0.0, S = 0.0;
    for (int t = 0; t < NV; ++t) {
      int vid = (int)sm.P[t];
      float vt = __uint_as_float(sm.K[t]);
      int r = vid / W_;
      int c = vid - r * W_;

      // candidate neighbor ranks; inactive chains parked at t (par[t]==t => no-op)
      int x0 = t, x1 = t, x2 = t, x3 = t;
      if (c > 0)      { int a = (int)sm.rk[vid - 1];  if (a < t) x0 = a; }
      if (c < W_ - 1) { int a = (int)sm.rk[vid + 1];  if (a < t) x1 = a; }
      if (r > 0)      { int a = (int)sm.rk[vid - W_]; if (a < t) x2 = a; }
      if (r < H_ - 1) { int a = (int)sm.rk[vid + W_]; if (a < t) x3 = a; }

      // 4-way interleaved root chase (overlaps LDS latency across chains)
      int o0 = x0, o1 = x1, o2 = x2, o3 = x3;
      for (;;) {
        int p0 = sm.par[x0], p1 = sm.par[x1], p2 = sm.par[x2], p3 = sm.par[x3];
        if (p0 == x0 && p1 == x1 && p2 == x2 && p3 == x3) break;
        x0 = p0; x1 = p1; x2 = p2; x3 = p3;
      }
      // start-compression
      if (o0 != x0) sm.par[o0] = (unsigned short)x0;
      if (o1 != x1) sm.par[o1] = (unsigned short)x1;
      if (o2 != x2) sm.par[o2] = (unsigned short)x2;
      if (o3 != x3) sm.par[o3] = (unsigned short)x3;

      int m = t;  // root of the growing component containing v
      #define MERGE_CHAIN(xi)                                                  \
      {                                                                        \
        int rr = xi;                                                           \
        for (;;) { int pp = sm.par[rr]; if (pp == rr) break; rr = pp; }        \
        if (rr != m) {                                                         \
          int young = rr > m ? rr : m;                                         \
          int old   = rr + m - young;                                          \
          sm.par[young] = (unsigned short)old;                                 \
          float pers = vt - __uint_as_float(sm.K[young]);                      \
          if (pers > 0.0f) {                                                   \
            T += (double)pers;                                                 \
            S += (double)(pers * logf(pers));                                  \
          }                                                                    \
          m = old;                                                             \
        }                                                                      \
      }
      MERGE_CHAIN(x0)
      MERGE_CHAIN(x1)
      MERGE_CHAIN(x2)
      MERGE_CHAIN(x3)
      #undef MERGE_CHAIN
    }
    out[blockIdx.x] = (T > 0.0) ? (float)(log(T) - S / T) : 0.0f;
  }
}

extern "C" void kernel_launch(void* const* d_in, const int* in_sizes, int n_in,
                              void* d_out, int out_size, void* d_ws, size_t ws_size,
                              hipStream_t stream) {
  (void)d_ws; (void)ws_size; (void)n_in;
  const float* x = (const float*)d_in[0];
  float* out = (float*)d_out;
  int n_img = in_sizes[0] / NV;   // 64
  if (n_img <= 0) n_img = 1;
  topo_entropy_kernel<<<n_img, NT, 0, stream>>>(x, out);
}

// Round 5
// 8085.615 us; speedup vs baseline: 1.1637x; 1.1637x over previous
//
#include <hip/hip_runtime.h>

#define H_ 96
#define W_ 96
#define NV (H_ * W_)      // 9216 vertices per image
#define SORT_N 16384      // next pow2 >= NV
#define NT 512            // threads per block

// LDS: 65536 (K) + 32768 (P) + 18432 (par) = 116736 B (fits 160 KiB/WG)
struct SMem {
  unsigned int   K[SORT_N];   // sortable keys; after phase 3: float bits of value at rank t
  unsigned short P[SORT_N];   // payload: vertex idx at rank t
  unsigned short par[NV];     // vid -> parent vid, or 0x8000|rank if root (elder = min rank)
};

__global__ __launch_bounds__(NT, 1)
void topo_entropy_kernel(const float* __restrict__ x, float* __restrict__ out) {
  __shared__ SMem sm;
  const int tid = threadIdx.x;
  const float* img = x + (size_t)blockIdx.x * NV;

  // ---- Phase 1: load values, build order-preserving u32 keys ----
  for (int i = tid; i < SORT_N; i += NT) {
    if (i < NV) {
      unsigned int b = __float_as_uint(img[i]);
      sm.K[i] = b ^ ((b & 0x80000000u) ? 0xFFFFFFFFu : 0x80000000u);
      sm.P[i] = (unsigned short)i;
    } else {
      sm.K[i] = 0xFFFFFFFFu;   // +inf padding -> sorts to tail
      sm.P[i] = 0xFFFFu;
    }
  }
  __syncthreads();

  // ---- Phase 2: bitonic sort ascending on (K, P), branchless CE ----
  for (int k = 2; k <= SORT_N; k <<= 1) {
    for (int j = k >> 1; j > 0; j >>= 1) {
      #pragma unroll 4
      for (int p = tid; p < (SORT_N / 2); p += NT) {
        int i = ((p & ~(j - 1)) << 1) | (p & (j - 1));
        int l = i | j;
        unsigned int ki = sm.K[i], kl = sm.K[l];
        unsigned short pi = sm.P[i], pl = sm.P[l];
        bool up = ((i & k) == 0);
        bool sw = up ? (ki > kl) : (ki < kl);
        sm.K[i] = sw ? kl : ki;
        sm.K[l] = sw ? ki : kl;
        sm.P[i] = sw ? pl : pi;
        sm.P[l] = sw ? pi : pl;
      }
      __syncthreads();
    }
  }

  // ---- Phase 3: keys -> float bits (rank->value); init par[v] = 0x8000|rank(v) ----
  for (int t = tid; t < NV; t += NT) {
    unsigned int key = sm.K[t];
    sm.K[t] = key ^ ((key & 0x80000000u) ? 0x80000000u : 0xFFFFFFFFu);
    sm.par[sm.P[t]] = (unsigned short)(0x8000u | (unsigned)t);
  }
  __syncthreads();

  // ---- Phase 4: serial Kruskal union-find over vertex order (elder = min rank) ----
  if (tid == 0) {
    double T = 0.0, S = 0.0;
    int vid_n = (int)sm.P[0];
    unsigned kb_n = sm.K[0];
    for (int t = 0; t < NV; ++t) {
      const int vid = vid_n;
      const float vt = __uint_as_float(kb_n);
      if (t + 1 < NV) {            // software-pipelined prefetch (hidden under chase)
        vid_n = (int)sm.P[t + 1];
        kb_n = sm.K[t + 1];
      }
      const int r = vid / W_;
      const int c = vid - r * W_;
      const int n0 = (c > 0)      ? vid - 1  : vid;
      const int n1 = (c < W_ - 1) ? vid + 1  : vid;
      const int n2 = (r > 0)      ? vid - W_ : vid;
      const int n3 = (r < H_ - 1) ? vid + W_ : vid;

      // 4-way interleaved root chase; roots carry their rank in the entry
      int x0 = n0, x1 = n1, x2 = n2, x3 = n3;
      unsigned p0, p1, p2, p3;
      for (;;) {
        p0 = sm.par[x0]; p1 = sm.par[x1]; p2 = sm.par[x2]; p3 = sm.par[x3];
        if (p0 & p1 & p2 & p3 & 0x8000u) break;
        x0 = (p0 & 0x8000u) ? x0 : (int)p0;
        x1 = (p1 & 0x8000u) ? x1 : (int)p1;
        x2 = (p2 & 0x8000u) ? x2 : (int)p2;
        x3 = (p3 & 0x8000u) ? x3 : (int)p3;
      }

      int mv = vid, mr = t;        // current component root (vid, rank)
      int g0 = -1, g1 = -1, g2 = -1;  // ex-roots merged this iteration (register set)

      #define DO_CHAIN(pc, xc)                                                   \
      {                                                                          \
        const int rr = (int)(pc & 0x7fffu);                                      \
        const int rv = xc;                                                       \
        if (rr <= t && rv != mv && rv != g0 && rv != g1 && rv != g2) {           \
          int yrank, yvid;                                                       \
          if (rr > mr) {                                                         \
            yrank = rr; yvid = rv;                                               \
            sm.par[rv] = (unsigned short)mv;                                     \
          } else {                                                               \
            yrank = mr; yvid = mv;                                               \
            sm.par[mv] = (unsigned short)rv;                                     \
            mv = rv; mr = rr;                                                    \
          }                                                                      \
          const float b = __uint_as_float(sm.K[yrank]);                          \
          const float pers = vt - b;                                             \
          if (pers > 0.0f) {                                                     \
            T += (double)pers;                                                   \
            S += (double)pers * (double)logf(pers);                              \
          }                                                                      \
          g2 = g1; g1 = g0; g0 = yvid;                                           \
        }                                                                        \
      }
      DO_CHAIN(p0, x0)
      DO_CHAIN(p1, x1)
      DO_CHAIN(p2, x2)
      DO_CHAIN(p3, x3)
      #undef DO_CHAIN

      // fire-and-forget path compression (no dependent reads)
      if ((int)(p0 & 0x7fffu) <= t) { if (n0 != mv) sm.par[n0] = (unsigned short)mv;
                                      if (x0 != mv && x0 != n0) sm.par[x0] = (unsigned short)mv; }
      if ((int)(p1 & 0x7fffu) <= t) { if (n1 != mv) sm.par[n1] = (unsigned short)mv;
                                      if (x1 != mv && x1 != n1) sm.par[x1] = (unsigned short)mv; }
      if ((int)(p2 & 0x7fffu) <= t) { if (n2 != mv) sm.par[n2] = (unsigned short)mv;
                                      if (x2 != mv && x2 != n2) sm.par[x2] = (unsigned short)mv; }
      if ((int)(p3 & 0x7fffu) <= t) { if (n3 != mv) sm.par[n3] = (unsigned short)mv;
                                      if (x3 != mv && x3 != n3) sm.par[x3] = (unsigned short)mv; }
      if (vid != mv) sm.par[vid] = (unsigned short)mv;
    }
    out[blockIdx.x] = (T > 0.0) ? (float)(log(T) - S / T) : 0.0f;
  }
}

extern "C" void kernel_launch(void* const* d_in, const int* in_sizes, int n_in,
                              void* d_out, int out_size, void* d_ws, size_t ws_size,
                              hipStream_t stream) {
  (void)d_ws; (void)ws_size; (void)n_in; (void)out_size;
  const float* x = (const float*)d_in[0];
  float* out = (float*)d_out;
  int n_img = in_sizes[0] / NV;   // 64
  if (n_img <= 0) n_img = 1;
  topo_entropy_kernel<<<n_img, NT, 0, stream>>>(x, out);
}

// Round 6
// 3418.624 us; speedup vs baseline: 2.7523x; 2.3652x over previous
//
#include <hip/hip_runtime.h>

#define H_ 96
#define W_ 96
#define NV (H_ * W_)              // 9216
#define SORT_N 16384
#define NT 512
#define NBANDS 8
#define BROWS (H_ / NBANDS)       // 12
#define BVERTS (BROWS * W_)       // 1152
#define DCAP 576                  // hard bound: merges/band <= births-1 < 576
#define NBE ((NBANDS - 1) * W_)   // 672 cross-band edges
#define BE_PAD 1024

// LDS 162976 B total (<= 160 KiB)
struct SMem {
  unsigned int   K[SORT_N];        // rank -> sortable key; tail reused for boundary-edge sort
  unsigned short P[SORT_N];        // rank -> vid; tail reused for anchors
  unsigned short parL[NV];         // vid -> parent vid | root: 0x8000 | taint<<14 | rank
  unsigned short BL[NV];           // bandlist (band-local rank order); later parG (rank-indexed UF)
  unsigned short dfr[NBANDS][DCAP * 3];  // deferred edges (w_rank, rootA_rank, rootB_rank)
  double bandT[NBANDS];
  double bandS[NBANDS];
  unsigned int dcnt[NBANDS];
};

__device__ __forceinline__ float keyToFloat(unsigned int k) {
  return __uint_as_float((k & 0x80000000u) ? (k ^ 0x80000000u) : ~k);
}

__global__ __launch_bounds__(NT, 1)
void topo_entropy_kernel(const float* __restrict__ x, float* __restrict__ out) {
  __shared__ SMem sm;
  const int tid = threadIdx.x;
  const float* img = x + (size_t)blockIdx.x * NV;

  unsigned int*   bkeys = &sm.K[NV];                          // [1024] u32
  unsigned short* bidx  = (unsigned short*)&sm.K[NV + BE_PAD];// [1024] u16
  unsigned short* baR   = bidx + BE_PAD;                      // [672]
  unsigned short* bbR   = baR + NBE;                          // [672]
  unsigned short* anchors = &sm.P[NV];                        // [1344]

  // ---- P1: load, order-preserving u32 keys ----
  for (int i = tid; i < SORT_N; i += NT) {
    if (i < NV) {
      unsigned int b = __float_as_uint(img[i]);
      sm.K[i] = b ^ ((b & 0x80000000u) ? 0xFFFFFFFFu : 0x80000000u);
      sm.P[i] = (unsigned short)i;
    } else { sm.K[i] = 0xFFFFFFFFu; sm.P[i] = 0xFFFFu; }
  }
  __syncthreads();

  // ---- P2: bitonic sort ascending (K, P) ----
  for (int k = 2; k <= SORT_N; k <<= 1) {
    for (int j = k >> 1; j > 0; j >>= 1) {
      #pragma unroll 4
      for (int p = tid; p < (SORT_N / 2); p += NT) {
        int i = ((p & ~(j - 1)) << 1) | (p & (j - 1));
        int l = i | j;
        unsigned int ki = sm.K[i], kl = sm.K[l];
        unsigned short pi = sm.P[i], pl = sm.P[l];
        bool up = ((i & k) == 0);
        bool sw = up ? (ki > kl) : (ki < kl);
        sm.K[i] = sw ? kl : ki;  sm.K[l] = sw ? ki : kl;
        sm.P[i] = sw ? pl : pi;  sm.P[l] = sw ? pi : pl;
      }
      __syncthreads();
    }
  }

  // ---- P3: parL init (root entries carry rank); P4: per-band rank lists ----
  for (int t = tid; t < NV; t += NT)
    sm.parL[sm.P[t]] = (unsigned short)(0x8000u | (unsigned int)t);
  if (tid < NBANDS) { sm.dcnt[tid] = 0u; sm.bandT[tid] = 0.0; sm.bandS[tid] = 0.0; }
  {
    const int wv = tid >> 6, lane = tid & 63;
    int cnt = 0;
    for (int t0 = 0; t0 < NV; t0 += 64) {
      const int t = t0 + lane;
      const int vid = (int)sm.P[t];
      const bool mine = (vid / BVERTS) == wv;   // band = vid/1152 (full-row bands)
      const unsigned long long m = __ballot(mine);
      if (mine)
        sm.BL[wv * BVERTS + cnt + __popcll(m & ((1ull << lane) - 1ull))] = (unsigned short)t;
      cnt += (int)__popcll(m);
    }
  }
  __syncthreads();

  // ---- P5: 8 parallel band-local Kruskal (lane 0 of each wave) ----
  if ((tid & 63) == 0) {
    const int b = tid >> 6;
    const int base = b * BVERTS;
    const int rtop = b * BROWS, rbot = rtop + BROWS - 1;
    unsigned short* db = &sm.dfr[b][0];
    double T = 0.0, S = 0.0;
    int dc = 0;
    int t_n = (int)sm.BL[base];
    for (int j = 0; j < BVERTS; ++j) {
      const int t = t_n;
      if (j + 1 < BVERTS) t_n = (int)sm.BL[base + j + 1];
      const int vid = (int)sm.P[t];
      const float vt = keyToFloat(sm.K[t]);
      const int r = vid / W_;
      const int c = vid - r * W_;
      int n0 = (c > 0)      ? vid - 1  : vid;
      int n1 = (c < W_ - 1) ? vid + 1  : vid;
      int n2 = (r > rtop)   ? vid - W_ : vid;
      int n3 = (r < rbot)   ? vid + W_ : vid;
      int x0 = n0, x1 = n1, x2 = n2, x3 = n3;
      unsigned int p0 = sm.parL[x0], p1 = sm.parL[x1], p2 = sm.parL[x2], p3 = sm.parL[x3];
      const unsigned int self = 0x8000u | (unsigned int)t;
      if ((p0 & 0x8000u) && (int)(p0 & 0x3FFFu) > t) { x0 = vid; n0 = vid; p0 = self; }
      if ((p1 & 0x8000u) && (int)(p1 & 0x3FFFu) > t) { x1 = vid; n1 = vid; p1 = self; }
      if ((p2 & 0x8000u) && (int)(p2 & 0x3FFFu) > t) { x2 = vid; n2 = vid; p2 = self; }
      if ((p3 & 0x8000u) && (int)(p3 & 0x3FFFu) > t) { x3 = vid; n3 = vid; p3 = self; }
      while (!((p0 & p1 & p2 & p3) & 0x8000u)) {
        x0 = (p0 & 0x8000u) ? x0 : (int)p0;
        x1 = (p1 & 0x8000u) ? x1 : (int)p1;
        x2 = (p2 & 0x8000u) ? x2 : (int)p2;
        x3 = (p3 & 0x8000u) ? x3 : (int)p3;
        p0 = sm.parL[x0]; p1 = sm.parL[x1]; p2 = sm.parL[x2]; p3 = sm.parL[x3];
      }
      int mv = vid, mr = t;
      unsigned int mtaint = ((r == rtop && b > 0) || (r == rbot && b < NBANDS - 1)) ? 1u : 0u;
      int g0 = -1, g1 = -1, g2 = -1;
      #define DO_CHAIN(pc, xc)                                                  \
      {                                                                         \
        const int rr = (int)(pc & 0x3FFFu);                                     \
        const unsigned int rt = (pc >> 14) & 1u;                                \
        const int rv = xc;                                                      \
        if (rr <= t && rv != mv && rv != g0 && rv != g1 && rv != g2) {          \
          int yR, yV; unsigned int yT;                                          \
          if (rr > mr) { yR = rr; yV = rv; yT = rt; }                           \
          else { yR = mr; yV = mv; yT = mtaint; mv = rv; mr = rr; }             \
          mtaint |= rt;                                                         \
          if (yT) {                                                             \
            db[dc * 3 + 0] = (unsigned short)t;                                 \
            db[dc * 3 + 1] = (unsigned short)yR;                                \
            db[dc * 3 + 2] = (unsigned short)mr;                                \
            ++dc;                                                               \
          } else {                                                              \
            const float pers = vt - keyToFloat(sm.K[yR]);                       \
            if (pers > 0.0f) { T += (double)pers;                               \
                               S += (double)(pers * logf(pers)); }              \
          }                                                                     \
          sm.parL[yV] = (unsigned short)mv;                                     \
          g2 = g1; g1 = g0; g0 = yV;                                            \
        }                                                                       \
      }
      DO_CHAIN(p0, x0)
      DO_CHAIN(p1, x1)
      DO_CHAIN(p2, x2)
      DO_CHAIN(p3, x3)
      #undef DO_CHAIN
      sm.parL[mv] = (unsigned short)(0x8000u | (mtaint << 14) | (unsigned int)mr);
      if (vid != mv) sm.parL[vid] = (unsigned short)mv;
      if ((int)(p0 & 0x3FFFu) <= t) { if (n0 != mv) sm.parL[n0] = (unsigned short)mv;
                                      if (x0 != mv && x0 != n0) sm.parL[x0] = (unsigned short)mv; }
      if ((int)(p1 & 0x3FFFu) <= t) { if (n1 != mv) sm.parL[n1] = (unsigned short)mv;
                                      if (x1 != mv && x1 != n1) sm.parL[x1] = (unsigned short)mv; }
      if ((int)(p2 & 0x3FFFu) <= t) { if (n2 != mv) sm.parL[n2] = (unsigned short)mv;
                                      if (x2 != mv && x2 != n2) sm.parL[x2] = (unsigned short)mv; }
      if ((int)(p3 & 0x3FFFu) <= t) { if (n3 != mv) sm.parL[n3] = (unsigned short)mv;
                                      if (x3 != mv && x3 != n3) sm.parL[x3] = (unsigned short)mv; }
      if (r == rbot && b < NBANDS - 1) anchors[b * 192 + c] = (unsigned short)mr;
      if (r == rtop && b > 0)          anchors[(b - 1) * 192 + 96 + c] = (unsigned short)mr;
    }
    sm.bandT[b] = T; sm.bandS[b] = S; sm.dcnt[b] = (unsigned int)dc;
  }
  __syncthreads();

  // ---- P6: boundary edges (anchor endpoints, key = max endpoint) + parG init ----
  for (int e = tid; e < BE_PAD; e += NT) {
    if (e < NBE) {
      const int cut = e / W_;
      const int col = e - cut * W_;
      const int u = (cut * BROWS + BROWS - 1) * W_ + col;
      const unsigned int bu = __float_as_uint(img[u]);
      const unsigned int bd = __float_as_uint(img[u + W_]);
      const unsigned int ku = bu ^ ((bu & 0x80000000u) ? 0xFFFFFFFFu : 0x80000000u);
      const unsigned int kd = bd ^ ((bd & 0x80000000u) ? 0xFFFFFFFFu : 0x80000000u);
      bkeys[e] = ku > kd ? ku : kd;
      bidx[e] = (unsigned short)e;
      baR[e] = anchors[cut * 192 + col];
      bbR[e] = anchors[cut * 192 + 96 + col];
    } else { bkeys[e] = 0xFFFFFFFFu; bidx[e] = 0xFFFFu; }
  }
  for (int r2 = tid; r2 < NV; r2 += NT)
    sm.BL[r2] = (unsigned short)(0x8000u | (unsigned int)r2);   // parG reuses BL
  __syncthreads();

  // ---- P7: sort boundary edges by key (bitonic 1024, one CE per thread) ----
  for (int k = 2; k <= BE_PAD; k <<= 1) {
    for (int j = k >> 1; j > 0; j >>= 1) {
      const int p = tid;           // 512 pairs exactly
      const int i = ((p & ~(j - 1)) << 1) | (p & (j - 1));
      const int l = i | j;
      unsigned int ki = bkeys[i], kl = bkeys[l];
      unsigned short ii = bidx[i], il = bidx[l];
      const bool up = ((i & k) == 0);
      const bool sw = up ? (ki > kl) : (ki < kl);
      bkeys[i] = sw ? kl : ki;  bkeys[l] = sw ? ki : kl;
      bidx[i] = sw ? il : ii;   bidx[l] = sw ? ii : il;
      __syncthreads();
    }
  }

  // ---- P8: serial global replay (9-way sorted-stream merge over parG) ----
  if (tid == 0) {
    double T = 0.0, S = 0.0;
    for (int b2 = 0; b2 < NBANDS; ++b2) { T += sm.bandT[b2]; S += sm.bandS[b2]; }
    int dp[NBANDS];
    unsigned int hk[9]; int hA[9], hB[9];
    for (int s = 0; s < NBANDS; ++s) {
      dp[s] = 0;
      if ((unsigned)0 < sm.dcnt[s]) {
        const unsigned short* e = &sm.dfr[s][0];
        hA[s] = (int)e[1]; hB[s] = (int)e[2]; hk[s] = sm.K[e[0]];
      } else hk[s] = 0xFFFFFFFFu;
    }
    int bp = 0;
    {
      const unsigned int k0 = bkeys[0];
      if (k0 != 0xFFFFFFFFu) { const int id = (int)bidx[0]; hk[8] = k0; hA[8] = (int)baR[id]; hB[8] = (int)bbR[id]; }
      else hk[8] = 0xFFFFFFFFu;
    }
    for (;;) {
      int ms = 0; unsigned int mk = hk[0];
      #pragma unroll
      for (int s = 1; s < 9; ++s) if (hk[s] < mk) { mk = hk[s]; ms = s; }
      if (mk == 0xFFFFFFFFu) break;
      const int a = hA[ms], bb = hB[ms];
      int fa = a; for (;;) { const unsigned int e = sm.BL[fa]; if (e & 0x8000u) break; fa = (int)e; }
      int fb = bb; for (;;) { const unsigned int e = sm.BL[fb]; if (e & 0x8000u) break; fb = (int)e; }
      if (fa != fb) {
        const int y = fa > fb ? fa : fb;
        const int el = fa + fb - y;
        const float pers = keyToFloat(mk) - keyToFloat(sm.K[y]);
        if (pers > 0.0f) { T += (double)pers; S += (double)(pers * logf(pers)); }
        sm.BL[y] = (unsigned short)el;
        if (a != fa && a != y)  sm.BL[a]  = (unsigned short)el;
        if (bb != fb && bb != y) sm.BL[bb] = (unsigned short)el;
      } else {
        if (a != fa)  sm.BL[a]  = (unsigned short)fa;
        if (bb != fb) sm.BL[bb] = (unsigned short)fb;
      }
      if (ms < NBANDS) {
        ++dp[ms];
        if ((unsigned)dp[ms] < sm.dcnt[ms]) {
          const unsigned short* e = &sm.dfr[ms][dp[ms] * 3];
          hA[ms] = (int)e[1]; hB[ms] = (int)e[2]; hk[ms] = sm.K[e[0]];
        } else hk[ms] = 0xFFFFFFFFu;
      } else {
        ++bp;
        const unsigned int kk = (bp < NBE) ? bkeys[bp] : 0xFFFFFFFFu;
        if (kk != 0xFFFFFFFFu) { const int id = (int)bidx[bp]; hk[8] = kk; hA[8] = (int)baR[id]; hB[8] = (int)bbR[id]; }
        else hk[8] = 0xFFFFFFFFu;
      }
    }
    out[blockIdx.x] = (T > 0.0) ? (float)(log(T) - S / T) : 0.0f;
  }
}

extern "C" void kernel_launch(void* const* d_in, const int* in_sizes, int n_in,
                              void* d_out, int out_size, void* d_ws, size_t ws_size,
                              hipStream_t stream) {
  (void)d_ws; (void)ws_size; (void)n_in; (void)out_size;
  const float* x = (const float*)d_in[0];
  float* out = (float*)d_out;
  int n_img = in_sizes[0] / NV;   // 64
  if (n_img <= 0) n_img = 1;
  topo_entropy_kernel<<<n_img, NT, 0, stream>>>(x, out);
}

// Round 9
// 2924.432 us; speedup vs baseline: 3.2174x; 1.1690x over previous
//
#include <hip/hip_runtime.h>

#define H_ 96
#define W_ 96
#define NV (H_ * W_)              // 9216
#define SORT_N 16384
#define NT 1024
#define NBANDS 16
#define BROWS (H_ / NBANDS)       // 6
#define BVERTS (BROWS * W_)       // 576
#define DCAP 288                  // deferred/band <= births-1 <= 287
#define NCUTS (NBANDS - 1)        // 15
#define NBE (NCUTS * W_)          // 1440
#define EV_MAX 8192

// LDS ~141 KB (<160 KiB). Lifetime-overlapped regions documented inline.
struct SMem {
  unsigned int   K[SORT_N];        // sortable keys by rank; tail [NV..) reused as dfr
  unsigned short P[SORT_N];        // rank->vid; tail = anchors; head reused as evAB (u32)
  unsigned short parL[NV];         // band UF (vid-indexed); reused as parG (rank-indexed)
  unsigned short BL[NV];           // band lists; reused as evR (u16[8192])
  unsigned short rkB[NCUTS * 192]; // boundary-row vid->rank (per cut: 96 upper, 96 lower)
  double bandT[NBANDS], bandS[NBANDS];
  unsigned int dcnt[NBANDS];
  unsigned int evCount, evM;
};

__device__ __forceinline__ float keyToFloat(unsigned int k) {
  return __uint_as_float((k & 0x80000000u) ? (k ^ 0x80000000u) : ~k);
}

__global__ __launch_bounds__(NT, 1)
void topo_entropy_kernel(const float* __restrict__ x, float* __restrict__ out) {
  __shared__ SMem sm;
  const int tid = threadIdx.x;
  const float* img = x + (size_t)blockIdx.x * NV;

  unsigned short* dfr     = (unsigned short*)&sm.K[NV];  // 16*288*3 u16 = 27648 B (K tail = 28672 B)
  unsigned short* anchors = &sm.P[NV];                   // 2880 u16
  unsigned short* evR     = sm.BL;                       // u16[8192]
  unsigned int*   evAB    = (unsigned int*)sm.P;         // u32[8192]

  // ---- P1: load, order-preserving u32 keys ----
  for (int i = tid; i < SORT_N; i += NT) {
    if (i < NV) {
      unsigned int b = __float_as_uint(img[i]);
      sm.K[i] = b ^ ((b & 0x80000000u) ? 0xFFFFFFFFu : 0x80000000u);
      sm.P[i] = (unsigned short)i;
    } else { sm.K[i] = 0xFFFFFFFFu; sm.P[i] = 0xFFFFu; }
  }
  if (tid < NBANDS) { sm.dcnt[tid] = 0u; sm.bandT[tid] = 0.0; sm.bandS[tid] = 0.0; }
  __syncthreads();

  // ---- P2: bitonic sort ascending (K, P) ----
  for (int k = 2; k <= SORT_N; k <<= 1) {
    for (int j = k >> 1; j > 0; j >>= 1) {
      #pragma unroll 4
      for (int p = tid; p < (SORT_N / 2); p += NT) {
        int i = ((p & ~(j - 1)) << 1) | (p & (j - 1));
        int l = i | j;
        unsigned int ki = sm.K[i], kl = sm.K[l];
        unsigned short pi = sm.P[i], pl = sm.P[l];
        bool up = ((i & k) == 0);
        bool sw = up ? (ki > kl) : (ki < kl);
        sm.K[i] = sw ? kl : ki;  sm.K[l] = sw ? ki : kl;
        sm.P[i] = sw ? pl : pi;  sm.P[l] = sw ? pi : pl;
      }
      __syncthreads();
    }
  }

  // ---- P3: parL root-init (rank in entry) + boundary-row rank LUT ----
  for (int t = tid; t < NV; t += NT) {
    const int vid = (int)sm.P[t];
    sm.parL[vid] = (unsigned short)(0x8000u | (unsigned int)t);
    const int r = vid / W_;
    const int c = vid - r * W_;
    if ((r % BROWS) == BROWS - 1 && r < H_ - 1) sm.rkB[(r / BROWS) * 192 + c] = (unsigned short)t;
    if ((r % BROWS) == 0 && r > 0)              sm.rkB[(r / BROWS - 1) * 192 + 96 + c] = (unsigned short)t;
  }
  // ---- P4: per-band rank lists (wave-cooperative compaction) ----
  {
    const int wv = tid >> 6, lane = tid & 63;
    int cnt = 0;
    for (int t0 = 0; t0 < NV; t0 += 64) {
      const int t = t0 + lane;
      const int vid = (int)sm.P[t];
      const bool mine = (vid / BVERTS) == wv;
      const unsigned long long m = __ballot(mine);
      if (mine)
        sm.BL[wv * BVERTS + cnt + __popcll(m & ((1ull << lane) - 1ull))] = (unsigned short)t;
      cnt += (int)__popcll(m);
    }
  }
  __syncthreads();

  // ---- P5: 16 parallel band-local Kruskal (lane 0 of each wave) ----
  if ((tid & 63) == 0) {
    const int b = tid >> 6;
    const int base = b * BVERTS;
    const int rtop = b * BROWS, rbot = rtop + BROWS - 1;
    unsigned short* db = &dfr[b * DCAP * 3];
    double T = 0.0, S = 0.0;
    int dc = 0;
    int t_n = (int)sm.BL[base];
    for (int j = 0; j < BVERTS; ++j) {
      const int t = t_n;
      if (j + 1 < BVERTS) t_n = (int)sm.BL[base + j + 1];
      const int vid = (int)sm.P[t];
      const float vt = keyToFloat(sm.K[t]);
      const int r = vid / W_;
      const int c = vid - r * W_;
      int n0 = (c > 0)      ? vid - 1  : vid;
      int n1 = (c < W_ - 1) ? vid + 1  : vid;
      int n2 = (r > rtop)   ? vid - W_ : vid;
      int n3 = (r < rbot)   ? vid + W_ : vid;
      int x0 = n0, x1 = n1, x2 = n2, x3 = n3;
      unsigned int p0 = sm.parL[x0], p1 = sm.parL[x1], p2 = sm.parL[x2], p3 = sm.parL[x3];
      const unsigned int self = 0x8000u | (unsigned int)t;
      if ((p0 & 0x8000u) && (int)(p0 & 0x3FFFu) > t) { x0 = vid; n0 = vid; p0 = self; }
      if ((p1 & 0x8000u) && (int)(p1 & 0x3FFFu) > t) { x1 = vid; n1 = vid; p1 = self; }
      if ((p2 & 0x8000u) && (int)(p2 & 0x3FFFu) > t) { x2 = vid; n2 = vid; p2 = self; }
      if ((p3 & 0x8000u) && (int)(p3 & 0x3FFFu) > t) { x3 = vid; n3 = vid; p3 = self; }
      while (!((p0 & p1 & p2 & p3) & 0x8000u)) {
        x0 = (p0 & 0x8000u) ? x0 : (int)p0;
        x1 = (p1 & 0x8000u) ? x1 : (int)p1;
        x2 = (p2 & 0x8000u) ? x2 : (int)p2;
        x3 = (p3 & 0x8000u) ? x3 : (int)p3;
        p0 = sm.parL[x0]; p1 = sm.parL[x1]; p2 = sm.parL[x2]; p3 = sm.parL[x3];
      }
      int mv = vid, mr = t;
      unsigned int mtaint = ((r == rtop && b > 0) || (r == rbot && b < NBANDS - 1)) ? 1u : 0u;
      int g0 = -1, g1 = -1, g2 = -1;
      #define DO_CHAIN(pc, xc)                                                  \
      {                                                                         \
        const int rr = (int)(pc & 0x3FFFu);                                     \
        const unsigned int rt = (pc >> 14) & 1u;                                \
        const int rv = xc;                                                      \
        if (rr <= t && rv != mv && rv != g0 && rv != g1 && rv != g2) {          \
          int yR, yV; unsigned int yT;                                          \
          if (rr > mr) { yR = rr; yV = rv; yT = rt; }                           \
          else { yR = mr; yV = mv; yT = mtaint; mv = rv; mr = rr; }             \
          mtaint |= rt;                                                         \
          if (yT) {                                                             \
            db[dc * 3 + 0] = (unsigned short)t;                                 \
            db[dc * 3 + 1] = (unsigned short)yR;                                \
            db[dc * 3 + 2] = (unsigned short)mr;                                \
            ++dc;                                                               \
          } else {                                                              \
            const float pers = vt - keyToFloat(sm.K[yR]);                       \
            if (pers > 0.0f) { T += (double)pers;                               \
                               S += (double)(pers * logf(pers)); }              \
          }                                                                     \
          sm.parL[yV] = (unsigned short)mv;                                     \
          g2 = g1; g1 = g0; g0 = yV;                                            \
        }                                                                       \
      }
      DO_CHAIN(p0, x0)
      DO_CHAIN(p1, x1)
      DO_CHAIN(p2, x2)
      DO_CHAIN(p3, x3)
      #undef DO_CHAIN
      sm.parL[mv] = (unsigned short)(0x8000u | (mtaint << 14) | (unsigned int)mr);
      if (vid != mv) sm.parL[vid] = (unsigned short)mv;
      if ((int)(p0 & 0x3FFFu) <= t) { if (n0 != mv) sm.parL[n0] = (unsigned short)mv;
                                      if (x0 != mv && x0 != n0) sm.parL[x0] = (unsigned short)mv; }
      if ((int)(p1 & 0x3FFFu) <= t) { if (n1 != mv) sm.parL[n1] = (unsigned short)mv;
                                      if (x1 != mv && x1 != n1) sm.parL[x1] = (unsigned short)mv; }
      if ((int)(p2 & 0x3FFFu) <= t) { if (n2 != mv) sm.parL[n2] = (unsigned short)mv;
                                      if (x2 != mv && x2 != n2) sm.parL[x2] = (unsigned short)mv; }
      if ((int)(p3 & 0x3FFFu) <= t) { if (n3 != mv) sm.parL[n3] = (unsigned short)mv;
                                      if (x3 != mv && x3 != n3) sm.parL[x3] = (unsigned short)mv; }
      if (r == rbot && b < NBANDS - 1) anchors[b * 192 + c] = (unsigned short)mr;
      if (r == rtop && b > 0)          anchors[(b - 1) * 192 + 96 + c] = (unsigned short)mr;
    }
    sm.bandT[b] = T; sm.bandS[b] = S; sm.dcnt[b] = (unsigned int)dc;
  }
  __syncthreads();

  // ---- P6a: boundary events (rank keys via rkB, anchors payload) + parG init ----
  for (int e = tid; e < NBE; e += NT) {
    const int cut = e / W_;
    const int col = e - cut * W_;
    const unsigned short ru = sm.rkB[cut * 192 + col];
    const unsigned short rv = sm.rkB[cut * 192 + 96 + col];
    evR[e] = ru > rv ? ru : rv;
    evAB[e] = ((unsigned int)anchors[cut * 192 + col] << 16) | anchors[cut * 192 + 96 + col];
  }
  for (int r2 = tid; r2 < NV; r2 += NT) sm.parL[r2] = (unsigned short)0x8000u;  // parG
  if (tid == 0) {
    unsigned int c = NBE;
    for (int b2 = 0; b2 < NBANDS; ++b2) c += sm.dcnt[b2];
    sm.evCount = c;
    unsigned int M = 2048;
    while (M < c) M <<= 1;
    sm.evM = M;
  }
  __syncthreads();

  // ---- P6b: compact deferred events + pad ----
  {
    const int cnt = (int)sm.evCount;
    const int M = (int)sm.evM;
    for (int s = tid; s < NBANDS * DCAP; s += NT) {
      const int b2 = s / DCAP;
      const int i2 = s - b2 * DCAP;
      if ((unsigned)i2 < sm.dcnt[b2]) {
        int off = NBE;
        for (int q = 0; q < b2; ++q) off += (int)sm.dcnt[q];
        const unsigned short* e3 = &dfr[(b2 * DCAP + i2) * 3];
        evR[off + i2] = e3[0];
        evAB[off + i2] = ((unsigned int)e3[1] << 16) | e3[2];
      }
    }
    for (int e = cnt + tid; e < M; e += NT) evR[e] = 0xFFFFu;
  }
  __syncthreads();

  // ---- P7: bitonic sort events by rank key (runtime size M) ----
  {
    const int M = (int)sm.evM;
    for (int k = 2; k <= M; k <<= 1) {
      for (int j = k >> 1; j > 0; j >>= 1) {
        for (int p = tid; p < (M >> 1); p += NT) {
          const int i = ((p & ~(j - 1)) << 1) | (p & (j - 1));
          const int l = i | j;
          const unsigned short ki = evR[i], kl = evR[l];
          const unsigned int ai = evAB[i], al = evAB[l];
          const bool up = ((i & k) == 0);
          const bool sw = up ? (ki > kl) : (ki < kl);
          evR[i] = sw ? kl : ki;  evR[l] = sw ? ki : kl;
          evAB[i] = sw ? al : ai; evAB[l] = sw ? ai : al;
        }
        __syncthreads();
      }
    }
  }

  // ---- P8: serial linear replay over sorted events ----
  if (tid == 0) {
    double T = 0.0, S = 0.0;
    for (int b2 = 0; b2 < NBANDS; ++b2) { T += sm.bandT[b2]; S += sm.bandS[b2]; }
    const int cnt = (int)sm.evCount;
    unsigned short wn = evR[0];
    unsigned int abn = evAB[0];
    float dvn = keyToFloat(sm.K[wn]);
    for (int i = 0; i < cnt; ++i) {
      const unsigned int ab = abn;
      const float dv = dvn;
      if (i + 1 < cnt) {               // prefetch next event (hides LDS latency)
        wn = evR[i + 1]; abn = evAB[i + 1]; dvn = keyToFloat(sm.K[wn]);
      }
      const int a = (int)(ab >> 16), b2 = (int)(ab & 0xFFFFu);
      int fa = a, fb = b2;
      unsigned int ea = sm.parL[fa], eb = sm.parL[fb];
      while (!((ea & eb) & 0x8000u)) {
        fa = (ea & 0x8000u) ? fa : (int)ea;
        fb = (eb & 0x8000u) ? fb : (int)eb;
        ea = sm.parL[fa]; eb = sm.parL[fb];
      }
      if (fa != fb) {
        const int y = fa > fb ? fa : fb;
        const int el = fa + fb - y;
        const float pers = dv - keyToFloat(sm.K[y]);
        if (pers > 0.0f) { T += (double)pers; S += (double)(pers * logf(pers)); }
        sm.parL[y] = (unsigned short)el;
        if (a != el && a != y)   sm.parL[a]  = (unsigned short)el;
        if (b2 != el && b2 != y) sm.parL[b2] = (unsigned short)el;
      } else {
        if (a != fa)  sm.parL[a]  = (unsigned short)fa;
        if (b2 != fb) sm.parL[b2] = (unsigned short)fb;
      }
    }
    out[blockIdx.x] = (T > 0.0) ? (float)(log(T) - S / T) : 0.0f;
  }
}

extern "C" void kernel_launch(void* const* d_in, const int* in_sizes, int n_in,
                              void* d_out, int out_size, void* d_ws, size_t ws_size,
                              hipStream_t stream) {
  (void)d_ws; (void)ws_size; (void)n_in; (void)out_size;
  const float* x = (const float*)d_in[0];
  float* out = (float*)d_out;
  int n_img = in_sizes[0] / NV;   // 64
  if (n_img <= 0) n_img = 1;
  topo_entropy_kernel<<<n_img, NT, 0, stream>>>(x, out);
}